// Round 10
// baseline (266.728 us; speedup 1.0000x reference)
//
#include <hip/hip_runtime.h>
#include <stdint.h>

// Binarized 3-layer CNN — bit-exact vs float32 reference (verified r3-r8).
// L1: MFMA bf16x3-split conv (exact products, f32 accum) + guard band 4e-3 +
//     exact-sequential repair kernel for flagged (~1%) pixels.
//     r9 bug fixed: per-wave LDS base now includes wv*68*24 row offset.
// L2: XOR+popcount vs NEGATIVE masks, asm bcnt/alignbit (r8, verified).
// L3: masked-popcount ternary conv (r8, verified).

#define H1 510
#define H2 508
#define H3 506
#define STRIDE 512

typedef short bf16x8 __attribute__((ext_vector_type(8)));
typedef float f32x4 __attribute__((ext_vector_type(4)));

#define BCNT_ACC(acc, x) \
    asm("v_bcnt_u32_b32 %0, %1, %0" : "+v"(acc) : "v"(x))
#define FUNNEL31(word, val) \
    asm("v_alignbit_b32 %0, %0, %1, 31" : "+v"(word) : "v"(val))

__global__ __launch_bounds__(256) void k_prep(const float* __restrict__ w1,
                                              const float* __restrict__ w2,
                                              const float* __restrict__ w3,
                                              float* __restrict__ lw,
                                              uint32_t* __restrict__ pw2,
                                              uint32_t* __restrict__ pw3,
                                              uint32_t* __restrict__ atab,
                                              uint32_t* __restrict__ offtab) {
    int t = threadIdx.x;
    // sign(w1) f32, order t=(r*3+j)*3+c (c fastest), padded to 28/o  [repair uses]
    for (int i = t; i < 448; i += 256) {
        int o = i / 28, k = i % 28;
        float v = 0.f;
        if (k < 27) {
            int c = k % 3, j = (k / 3) % 3, r = k / 9;
            float wv = w1[o * 27 + c * 9 + r * 3 + j];
            v = (wv > 0.f) ? 1.f : ((wv < 0.f) ? -1.f : 0.f);
        }
        lw[i] = v;
    }
    // A-fragment table: lane (m=lane&15 -> o, g=lane>>4), elem e -> tap t=8g+e.
    // Same frag for all 3 split-calls (weight independent of split component).
    for (int i = t; i < 256; i += 256) {   // i = lane*4 + q
        int lane = i >> 2, q = i & 3;
        int m = lane & 15, g = lane >> 4;
        uint32_t dw = 0;
        for (int half = 0; half < 2; ++half) {
            int e = 2 * q + half;
            int tt = 8 * g + e;
            uint32_t bb = 0;
            if (tt < 27) {
                int c = tt % 3, j = (tt / 3) % 3, r = tt / 9;
                float wv = w1[m * 27 + c * 9 + r * 3 + j];
                bb = (wv > 0.f) ? 0x3F80u : ((wv < 0.f) ? 0xBF80u : 0u);
            }
            dw |= bb << (16 * half);
        }
        atab[i] = dw;
    }
    // LDS byte-offset per tap t (quad layout ((r*68+col)*3+c)*8); pad t>=27 -> 0
    for (int i = t; i < 32; i += 256) {
        uint32_t off = 0;
        if (i < 27) {
            int c = i % 3, j = (i / 3) % 3, r = i / 9;
            off = (uint32_t)((r * 68 + j) * 24 + c * 8);
        }
        offtab[i] = off;
    }
    // w2 neg-masks (r8)
    for (int i = t; i < 184; i += 256) {
        int o = i / 8, g = i % 8;
        uint32_t word = 0;
        if (g < 5) {
            int k0 = 2 * g, k1 = 2 * g + 1;
            for (int c = 0; c < 16; ++c) {
                if (!(w2[o * 144 + c * 9 + k0] > 0.f)) word |= 1u << c;
                if (k1 < 9 && !(w2[o * 144 + c * 9 + k1] > 0.f)) word |= 1u << (16 + c);
            }
        }
        pw2[i] = word;
    }
    // w3 pos-masks (r8)
    for (int i = t; i < 18; i += 256) {
        int o = i / 9, k = i % 9;
        uint32_t m = 0;
        for (int c = 0; c < 23; ++c)
            if (w3[o * 207 + c * 9 + k] > 0.f) m |= 1u << c;
        pw3[i] = m;
    }
}

// L1 via MFMA. Block: 64 px wide x 4 rows (1 wave/row, 4 tiles of 16 px each).
__global__ __launch_bounds__(256) void k_conv1(const float* __restrict__ in,
                                               const uint32_t* __restrict__ atab,
                                               const uint32_t* __restrict__ offtab,
                                               uint32_t* __restrict__ t1,
                                               uint16_t* __restrict__ fmap) {
    __shared__ __align__(16) char lds[6 * 68 * 3 * 8];   // split quads (h|m, l|0)
    int tid = threadIdx.x;
    int b = blockIdx.z;
    int w0 = blockIdx.x * 64;
    int h0 = blockIdx.y * 4;
    const float* base = in + (size_t)b * 3 * 512 * 512;
    // Stage: 6 rows x 66 cols x 3 ch, exact 3-way bf16 split via mask-truncation.
    for (int s = tid; s < 1188; s += 256) {
        int chunk = s / 66, col = s % 66;
        int r = chunk / 3, c = chunk % 3;
        int gr = h0 + r, gc = w0 + col;
        float x = 0.f;
        if (gr < 512 && gc < 512) x = base[c * 262144 + (size_t)gr * 512 + gc];
        uint32_t xb = __float_as_uint(x);
        uint32_t hb = xb & 0xFFFF0000u;
        float r1 = x - __uint_as_float(hb);
        uint32_t r1b = __float_as_uint(r1);
        uint32_t mb = r1b & 0xFFFF0000u;
        float r2 = r1 - __uint_as_float(mb);
        uint32_t d0 = (hb >> 16) | mb;                 // h16 | m16<<16
        uint32_t d1 = __float_as_uint(r2) >> 16;       // l16 (exact bf16)
        *(uint2*)(lds + ((r * 68 + col) * 3 + c) * 8) = make_uint2(d0, d1);
    }
    __syncthreads();
    int wv = tid >> 6;
    int lane = tid & 63;
    int h = h0 + wv;
    int m15 = lane & 15, g = lane >> 4;
    union { uint32_t d[4]; bf16x8 v; } af;
    {
        uint4 q = *(const uint4*)(atab + lane * 4);
        af.d[0] = q.x; af.d[1] = q.y; af.d[2] = q.z; af.d[3] = q.w;
    }
    uint4 oA = *(const uint4*)(offtab + 8 * g);
    uint4 oB = *(const uint4*)(offtab + 8 * g + 4);
    uint32_t offs[8] = {oA.x, oA.y, oA.z, oA.w, oB.x, oB.y, oB.z, oB.w};
    if (h < H1) {
        for (int ti = 0; ti < 4; ++ti) {
            // FIX (r9 bug): include the wave's row offset wv*68*24 in the base.
            uint32_t pbase = (uint32_t)(wv * 1632 + (ti * 16 + m15) * 24);
            uint2 q[8];
#pragma unroll
            for (int e = 0; e < 8; ++e)
                q[e] = *(const uint2*)(lds + pbase + offs[e]);
            union { uint32_t d[4]; bf16x8 v; } fh, fm, fl;
#pragma unroll
            for (int j = 0; j < 4; ++j) {
                fh.d[j] = __builtin_amdgcn_perm(q[2 * j + 1].x, q[2 * j].x, 0x05040100u);
                fm.d[j] = __builtin_amdgcn_perm(q[2 * j + 1].x, q[2 * j].x, 0x07060302u);
                fl.d[j] = __builtin_amdgcn_perm(q[2 * j + 1].y, q[2 * j].y, 0x05040100u);
            }
            f32x4 acc = {0.f, 0.f, 0.f, 0.f};
            acc = __builtin_amdgcn_mfma_f32_16x16x32_bf16(af.v, fh.v, acc, 0, 0, 0);
            acc = __builtin_amdgcn_mfma_f32_16x16x32_bf16(af.v, fm.v, acc, 0, 0, 0);
            acc = __builtin_amdgcn_mfma_f32_16x16x32_bf16(af.v, fl.v, acc, 0, 0, 0);
            // C: col=lane&15 (px), row=4*(lane>>4)+reg (o)  [m89-verified]
            uint32_t nib = 0, flg = 0;
#pragma unroll
            for (int rg = 0; rg < 4; ++rg) {
                float cv = acc[rg];
                nib |= (__float_as_uint(cv) >> 31) << rg;
                flg |= (uint32_t)(__builtin_fabsf(cv) < 4e-3f) << rg;
            }
            uint32_t val = (nib << (4 * g)) | (flg << (16 + 4 * g));
            val |= (uint32_t)__shfl_xor((int)val, 16);
            val |= (uint32_t)__shfl_xor((int)val, 32);
            int px = w0 + ti * 16 + m15;
            bool fl2 = (g == 0) && ((val >> 16) != 0) && (px < H1);
            unsigned long long bt = __ballot(fl2);
            if (g == 0 && px < H1)
                t1[(size_t)b * H1 * STRIDE + (size_t)h * STRIDE + px] = val & 0xFFFFu;
            if (lane == 0)
                fmap[((size_t)b * H1 + h) * 32 + (w0 >> 4) + ti] = (uint16_t)bt;
        }
    }
}

// Exact-sequential recompute of flagged pixels (rare ~1%). r8-proven math.
__global__ __launch_bounds__(256) void k_repair(const float* __restrict__ in,
                                                const float* __restrict__ lw_g,
                                                const uint16_t* __restrict__ fmap,
                                                uint32_t* __restrict__ t1) {
    int w = blockIdx.x * 256 + threadIdx.x;
    int h = blockIdx.y, b = blockIdx.z;
    if (w >= H1) return;
    uint16_t fw = fmap[((size_t)b * H1 + h) * 32 + (w >> 4)];
    if (!((fw >> (w & 15)) & 1)) return;
    const float* basep = in + (size_t)b * 3 * 512 * 512;
    float x[27];
    for (int c = 0; c < 3; ++c)
        for (int r = 0; r < 3; ++r)
            for (int j = 0; j < 3; ++j)
                x[c * 9 + r * 3 + j] = basep[c * 262144 + (size_t)(h + r) * 512 + (w + j)];
    uint32_t rn = 0, rz = 0;
    for (int o = 15; o >= 0; --o) {
        const float* wo = lw_g + o * 28;
        float s = 0.f;
        for (int t = 0; t < 27; ++t) {       // ascending t = (kh,kw,c), c fastest
            int c = t % 3, j = (t / 3) % 3, r = t / 9;
            s = fmaf(x[c * 9 + r * 3 + j], wo[t], s);
        }
        uint32_t u = __float_as_uint(s);
        rn = (rn << 1) | (u >> 31);
        uint32_t nz = u | (0u - u);
        rz = (rz << 1) | (nz >> 31);
    }
    t1[(size_t)b * H1 * STRIDE + (size_t)h * STRIDE + w] = rn | (~rz << 16);
}

// ---- conv2 / conv3: r8 verbatim ----
__global__ __launch_bounds__(256) void k_conv2(const uint32_t* __restrict__ t1,
                                               const uint32_t* __restrict__ pw2g,
                                               uint32_t* __restrict__ p2,
                                               uint32_t* __restrict__ m2) {
    __shared__ __align__(16) uint32_t wq[184];
    {
        int tid = threadIdx.y * 64 + threadIdx.x;
        for (int i = tid; i < 184; i += 256) wq[i] = pw2g[i];
    }
    __syncthreads();
    int w = blockIdx.x * 64 + threadIdx.x;
    int h = blockIdx.y * 4 + threadIdx.y;
    int b = blockIdx.z;
    if (w >= H2 || h >= H2) return;
    const uint32_t* base = t1 + (size_t)b * H1 * STRIDE;
    uint32_t A[9];
#pragma unroll
    for (int r = 0; r < 3; ++r)
#pragma unroll
        for (int j = 0; j < 3; ++j)
            A[r * 3 + j] = base[(size_t)(h + r) * STRIDE + (w + j)];
    uint32_t orall = A[0] | A[1] | A[2] | A[3] | A[4] | A[5] | A[6] | A[7] | A[8];
    uint32_t N0 = __builtin_amdgcn_perm(A[1], A[0], 0x05040100u);
    uint32_t N1 = __builtin_amdgcn_perm(A[3], A[2], 0x05040100u);
    uint32_t N2 = __builtin_amdgcn_perm(A[5], A[4], 0x05040100u);
    uint32_t N3 = __builtin_amdgcn_perm(A[7], A[6], 0x05040100u);
    uint32_t N4 = A[8] & 0xFFFFu;
    uint32_t plus = 0, minus = 0;
    if ((orall >> 16) == 0) {
#pragma unroll
        for (int o = 22; o >= 0; --o) {
            uint4 q = *(const uint4*)&wq[o * 8];
            uint32_t q4 = wq[o * 8 + 4];
            uint32_t t0 = N0 ^ q.x, t1x = N1 ^ q.y, t2 = N2 ^ q.z,
                     t3 = N3 ^ q.w, t4 = N4 ^ q4;
            int cnt = -72;
            BCNT_ACC(cnt, t0);
            BCNT_ACC(cnt, t1x);
            BCNT_ACC(cnt, t2);
            BCNT_ACC(cnt, t3);
            BCNT_ACC(cnt, t4);
            int nd = -cnt;
            FUNNEL31(plus, cnt);
            FUNNEL31(minus, nd);
        }
    } else {
        uint32_t P[5], M[5];
        {
            uint32_t p16[9], m16[9];
#pragma unroll
            for (int k = 0; k < 9; ++k) {
                uint32_t z = A[k] >> 16;
                p16[k] = (~(A[k] | z)) & 0xFFFFu;
                m16[k] = (A[k] & ~z) & 0xFFFFu;
            }
            P[0] = p16[0] | (p16[1] << 16); M[0] = m16[0] | (m16[1] << 16);
            P[1] = p16[2] | (p16[3] << 16); M[1] = m16[2] | (m16[3] << 16);
            P[2] = p16[4] | (p16[5] << 16); M[2] = m16[4] | (m16[5] << 16);
            P[3] = p16[6] | (p16[7] << 16); M[3] = m16[6] | (m16[7] << 16);
            P[4] = p16[8];                  M[4] = m16[8];
        }
        int sp = 0, sm = 0;
#pragma unroll
        for (int g = 0; g < 5; ++g) {
            sp += __builtin_popcount(P[g]);
            sm += __builtin_popcount(M[g]);
        }
#pragma unroll
        for (int o = 0; o < 23; ++o) {
            int ap = 0, am = 0;
#pragma unroll
            for (int g = 0; g < 5; ++g) {
                uint32_t Wn = wq[o * 8 + g];
                ap += __builtin_popcount(P[g] & Wn);
                am += __builtin_popcount(M[g] & Wn);
            }
            int s = sp - sm + 2 * (am - ap);
            plus  |= (uint32_t)(s > 0) << o;
            minus |= (uint32_t)(s < 0) << o;
        }
    }
    size_t idx = (size_t)b * H2 * STRIDE + (size_t)h * STRIDE + w;
    p2[idx] = plus;
    m2[idx] = minus;
}

__global__ __launch_bounds__(256) void k_conv3(const uint32_t* __restrict__ p2,
                                               const uint32_t* __restrict__ m2,
                                               const uint32_t* __restrict__ pw3,
                                               float* __restrict__ out) {
    int gx = blockIdx.x * 64 + threadIdx.x;
    int h = blockIdx.y * 4 + threadIdx.y;
    int b = blockIdx.z;
    int w0 = gx * 4;
    if (w0 >= H2 || h >= H3) return;
    const uint32_t* pb = p2 + (size_t)b * H2 * STRIDE;
    const uint32_t* mb = m2 + (size_t)b * H2 * STRIDE;
    uint32_t pp[3][6], mm[3][6];
#pragma unroll
    for (int r = 0; r < 3; ++r) {
        const uint32_t* rp = pb + (size_t)(h + r) * STRIDE + w0;
        uint4 q = *(const uint4*)rp;
        uint2 q2 = *(const uint2*)(rp + 4);
        pp[r][0] = q.x; pp[r][1] = q.y; pp[r][2] = q.z; pp[r][3] = q.w;
        pp[r][4] = q2.x; pp[r][5] = q2.y;
        const uint32_t* rm = mb + (size_t)(h + r) * STRIDE + w0;
        uint4 u = *(const uint4*)rm;
        uint2 u2 = *(const uint2*)(rm + 4);
        mm[r][0] = u.x; mm[r][1] = u.y; mm[r][2] = u.z; mm[r][3] = u.w;
        mm[r][4] = u2.x; mm[r][5] = u2.y;
    }
    float val[2][4];
#pragma unroll
    for (int i = 0; i < 4; ++i) {
        int Ps = 0, Ms = 0;
#pragma unroll
        for (int r = 0; r < 3; ++r)
#pragma unroll
            for (int j = 0; j < 3; ++j) {
                BCNT_ACC(Ps, pp[r][i + j]);
                BCNT_ACC(Ms, mm[r][i + j]);
            }
#pragma unroll
        for (int o = 0; o < 2; ++o) {
            int Ap = 0, Am = 0;
#pragma unroll
            for (int r = 0; r < 3; ++r)
#pragma unroll
                for (int j = 0; j < 3; ++j) {
                    uint32_t wm = pw3[o * 9 + r * 3 + j];
                    uint32_t ta = pp[r][i + j] & wm;
                    uint32_t tb = mm[r][i + j] & wm;
                    BCNT_ACC(Ap, ta);
                    BCNT_ACC(Am, tb);
                }
            int s = 2 * (Ap - Am) - Ps + Ms;
            val[o][i] = (s > 0) ? 1.f : ((s < 0) ? -1.f : 0.f);
        }
    }
#pragma unroll
    for (int o = 0; o < 2; ++o) {
        float* op = out + (size_t)b * (2 * H3 * H3) + (size_t)o * (H3 * H3) + (size_t)h * H3 + w0;
        *(float2*)op = make_float2(val[o][0], val[o][1]);
        if (w0 + 3 < H3)
            *(float2*)(op + 2) = make_float2(val[o][2], val[o][3]);
    }
}

extern "C" void kernel_launch(void* const* d_in, const int* in_sizes, int n_in,
                              void* d_out, int out_size, void* d_ws, size_t ws_size,
                              hipStream_t stream) {
    const float* inputs = (const float*)d_in[0];
    const float* w1 = (const float*)d_in[1];
    const float* w2 = (const float*)d_in[2];
    const float* w3 = (const float*)d_in[3];
    float* out = (float*)d_out;
    char* ws = (char*)d_ws;

    float* lw = (float*)(ws + 0);               // 448 f32
    uint32_t* pw2 = (uint32_t*)(ws + 2048);     // 184 u32
    uint32_t* pw3 = (uint32_t*)(ws + 4096);     // 18 u32
    uint32_t* atab = (uint32_t*)(ws + 4608);    // 256 u32 (A-frag table)
    uint32_t* offtab = (uint32_t*)(ws + 5632);  // 32 u32
    uint32_t* t1 = (uint32_t*)(ws + 8192);      // 32*510*512 u32
    size_t off_p2 = 8192 + (size_t)32 * H1 * STRIDE * 4;
    uint32_t* p2 = (uint32_t*)(ws + off_p2);    // 32*508*512 u32
    size_t off_m2 = off_p2 + (size_t)32 * H2 * STRIDE * 4;
    uint32_t* m2 = (uint32_t*)(ws + off_m2);
    size_t need = off_m2 + (size_t)32 * H2 * STRIDE * 4;
    if (ws_size < need) return;
    // Flag map (1.04 MB) overlaps p2: written by conv1, read by repair,
    // then p2 is overwritten by conv2. No extra workspace.
    uint16_t* fmap = (uint16_t*)(ws + off_p2);

    hipLaunchKernelGGL(k_prep, dim3(1), dim3(256), 0, stream,
                       w1, w2, w3, lw, pw2, pw3, atab, offtab);
    hipLaunchKernelGGL(k_conv1, dim3(8, 128, 32), dim3(256), 0, stream,
                       inputs, atab, offtab, t1, fmap);
    hipLaunchKernelGGL(k_repair, dim3(2, 510, 32), dim3(256), 0, stream,
                       inputs, lw, fmap, t1);
    hipLaunchKernelGGL(k_conv2, dim3(8, 127, 32), dim3(64, 4), 0, stream, t1, pw2, p2, m2);
    hipLaunchKernelGGL(k_conv3, dim3(2, 127, 32), dim3(64, 4), 0, stream, p2, m2, pw3, out);
}

// Round 11
// 207.878 us; speedup vs baseline: 1.2831x; 1.2831x over previous
//
#include <hip/hip_runtime.h>
#include <stdint.h>

// Binarized 3-layer CNN — bit-exact vs float32 reference (verified r3-r8, r10).
// L1: f32 conv, strict sequential (kh,kw,c) per-pixel order, 8 px/thread,
//     weights via wave-uniform s_load (r8-verified, VALU-issue floor).
// L2: XOR+popcount vs NEGATIVE masks, 2 px/thread (shared wq loads, b64
//     window loads, uint2 stores), asm bcnt/alignbit. Exact ternary fallback.
// L3: masked-popcount ternary conv, 4 px/thread (r8-verified).

#define H1 510
#define H2 508
#define H3 506
#define STRIDE 512

#define BCNT_ACC(acc, x) \
    asm("v_bcnt_u32_b32 %0, %1, %0" : "+v"(acc) : "v"(x))
#define FUNNEL31(word, val) \
    asm("v_alignbit_b32 %0, %0, %1, 31" : "+v"(word) : "v"(val))

__global__ __launch_bounds__(256) void k_prep(const float* __restrict__ w1,
                                              const float* __restrict__ w2,
                                              const float* __restrict__ w3,
                                              float* __restrict__ lw,
                                              uint32_t* __restrict__ pw2,
                                              uint32_t* __restrict__ pw3) {
    int t = threadIdx.x;
    // sign(w1), order t=(r*3+j)*3+c (c fastest), padded to 28/o
    for (int i = t; i < 448; i += 256) {
        int o = i / 28, k = i % 28;
        float v = 0.f;
        if (k < 27) {
            int c = k % 3, j = (k / 3) % 3, r = k / 9;
            float wv = w1[o * 27 + c * 9 + r * 3 + j];
            v = (wv > 0.f) ? 1.f : ((wv < 0.f) ? -1.f : 0.f);
        }
        lw[i] = v;
    }
    // w2 [23][16][3][3] -> pw2[o*8+g]: NEGATIVE-mask 16-bit channel words,
    // 2 taps/word (k0 lo16, k1 hi16), g<5; g==4 hi16 = 0.
    for (int i = t; i < 184; i += 256) {
        int o = i / 8, g = i % 8;
        uint32_t word = 0;
        if (g < 5) {
            int k0 = 2 * g, k1 = 2 * g + 1;
            for (int c = 0; c < 16; ++c) {
                if (!(w2[o * 144 + c * 9 + k0] > 0.f)) word |= 1u << c;
                if (k1 < 9 && !(w2[o * 144 + c * 9 + k1] > 0.f)) word |= 1u << (16 + c);
            }
        }
        pw2[i] = word;
    }
    // w3 [2][23][3][3] -> per (o, tap k): POSITIVE 23-bit channel mask
    for (int i = t; i < 18; i += 256) {
        int o = i / 9, k = i % 9;
        uint32_t m = 0;
        for (int c = 0; c < 23; ++c)
            if (w3[o * 207 + c * 9 + k] > 0.f) m |= 1u << c;
        pw3[i] = m;
    }
}

// 8 px/thread (4 wide x 2 tall); strict per-pixel (kh,kw,c) f32 order.
// Weights via wave-uniform global reads -> scalar loads on the SMEM pipe.
__global__ __launch_bounds__(256) void k_conv1(const float* __restrict__ in,
                                               const float* __restrict__ lw_g,
                                               uint32_t* __restrict__ t1) {
    int gx = blockIdx.x * 64 + threadIdx.x;   // 0..127
    int hy = blockIdx.y * 4 + threadIdx.y;    // 0..255
    int b = blockIdx.z;
    int w0 = gx * 4;                          // 0..508
    int h0 = hy * 2;                          // 0..510
    if (h0 >= H1) return;
    const float* base = in + (size_t)b * 3 * 512 * 512;
    float x[3][4][6];
    bool tail = (w0 + 4 >= 512);
#pragma unroll
    for (int c = 0; c < 3; ++c)
#pragma unroll
        for (int r = 0; r < 4; ++r) {
            const float* rp = base + c * 262144 + (size_t)(h0 + r) * 512 + w0;
            float4 v4 = *(const float4*)rp;
            x[c][r][0] = v4.x; x[c][r][1] = v4.y; x[c][r][2] = v4.z; x[c][r][3] = v4.w;
            if (!tail) {
                float2 v2 = *(const float2*)(rp + 4);
                x[c][r][4] = v2.x; x[c][r][5] = v2.y;
            } else {
                x[c][r][4] = 0.f; x[c][r][5] = 0.f;   // feeds only px >= H1 (unread)
            }
        }
    uint32_t rn[8] = {0, 0, 0, 0, 0, 0, 0, 0};   // sign-bit planes
    uint32_t rz[8] = {0, 0, 0, 0, 0, 0, 0, 0};   // NONZERO-bit planes
#pragma unroll 1
    for (int o = 15; o >= 0; --o) {              // o order irrelevant to rounding
        const float* wo = lw_g + o * 28;         // uniform address -> s_load
        float s[8];
#pragma unroll
        for (int p = 0; p < 8; ++p) s[p] = 0.f;
#pragma unroll
        for (int t = 0; t < 27; ++t) {           // ascending t = (r*3+j)*3+c
            float wv = wo[t];
            int c = t % 3, j = (t / 3) % 3, r = t / 9;
#pragma unroll
            for (int pr = 0; pr < 2; ++pr)
#pragma unroll
                for (int pc = 0; pc < 4; ++pc)
                    s[pr * 4 + pc] = fmaf(x[c][pr + r][pc + j], wv, s[pr * 4 + pc]);
        }
#pragma unroll
        for (int p = 0; p < 8; ++p) {
            uint32_t u = __float_as_uint(s[p]);
            rn[p] = (rn[p] << 1) | (u >> 31);
            uint32_t nz = u | (0u - u);          // sign set iff u != 0
            rz[p] = (rz[p] << 1) | (nz >> 31);
        }
    }
    uint32_t* dst = t1 + (size_t)b * H1 * STRIDE;
#pragma unroll
    for (int pr = 0; pr < 2; ++pr) {
        uint32_t w4[4];
#pragma unroll
        for (int pc = 0; pc < 4; ++pc)
            w4[pc] = rn[pr * 4 + pc] | (~rz[pr * 4 + pc] << 16);  // n lo16 | z hi16
        *(uint4*)(dst + (size_t)(h0 + pr) * STRIDE + w0) =
            make_uint4(w4[0], w4[1], w4[2], w4[3]);
    }
}

// 2 px/thread; pw2 (neg masks) in LDS, loads shared across the pair.
__global__ __launch_bounds__(256) void k_conv2(const uint32_t* __restrict__ t1,
                                               const uint32_t* __restrict__ pw2g,
                                               uint32_t* __restrict__ p2,
                                               uint32_t* __restrict__ m2) {
    __shared__ __align__(16) uint32_t wq[184];
    {
        int tid = threadIdx.y * 64 + threadIdx.x;
        for (int i = tid; i < 184; i += 256) wq[i] = pw2g[i];
    }
    __syncthreads();
    int gx = blockIdx.x * 64 + threadIdx.x;   // 0..255
    int h = blockIdx.y * 4 + threadIdx.y;     // 0..507
    int b = blockIdx.z;
    int w0 = gx * 2;                          // 0..510, even
    if (w0 >= H2 || h >= H2) return;          // w0 <= 506 -> px 506,507 valid
    const uint32_t* base = t1 + (size_t)b * H1 * STRIDE;
    uint32_t A[3][4];                         // cols w0..w0+3 (col 509 max, valid)
#pragma unroll
    for (int r = 0; r < 3; ++r) {
        const uint32_t* rp = base + (size_t)(h + r) * STRIDE + w0;
        uint2 a = *(const uint2*)rp;
        uint2 bq = *(const uint2*)(rp + 2);
        A[r][0] = a.x; A[r][1] = a.y; A[r][2] = bq.x; A[r][3] = bq.y;
    }
    uint32_t orall = 0;
#pragma unroll
    for (int r = 0; r < 3; ++r)
#pragma unroll
        for (int j = 0; j < 4; ++j) orall |= A[r][j];
    // n-plane per px i (window cols i..i+2), 2 taps/word via byte-perm
    uint32_t N[2][5];
#pragma unroll
    for (int i = 0; i < 2; ++i) {
        N[i][0] = __builtin_amdgcn_perm(A[0][i + 1], A[0][i], 0x05040100u);
        N[i][1] = __builtin_amdgcn_perm(A[1][i], A[0][i + 2], 0x05040100u);
        N[i][2] = __builtin_amdgcn_perm(A[1][i + 2], A[1][i + 1], 0x05040100u);
        N[i][3] = __builtin_amdgcn_perm(A[2][i + 1], A[2][i], 0x05040100u);
        N[i][4] = A[2][i + 2] & 0xFFFFu;
    }
    uint32_t plus0 = 0, minus0 = 0, plus1 = 0, minus1 = 0;
    if ((orall >> 16) == 0) {
        // FAST: all activations +-1. d = popc_mismatch - 72; bit o desc.
#pragma unroll
        for (int o = 22; o >= 0; --o) {
            uint4 q = *(const uint4*)&wq[o * 8];
            uint32_t q4 = wq[o * 8 + 4];
            uint32_t a0 = N[0][0] ^ q.x, a1 = N[0][1] ^ q.y, a2 = N[0][2] ^ q.z,
                     a3 = N[0][3] ^ q.w, a4 = N[0][4] ^ q4;
            uint32_t b0 = N[1][0] ^ q.x, b1 = N[1][1] ^ q.y, b2 = N[1][2] ^ q.z,
                     b3 = N[1][3] ^ q.w, b4 = N[1][4] ^ q4;
            int ca = -72, cb = -72;
            BCNT_ACC(ca, a0); BCNT_ACC(ca, a1); BCNT_ACC(ca, a2);
            BCNT_ACC(ca, a3); BCNT_ACC(ca, a4);
            BCNT_ACC(cb, b0); BCNT_ACC(cb, b1); BCNT_ACC(cb, b2);
            BCNT_ACC(cb, b3); BCNT_ACC(cb, b4);
            int na = -ca, nb = -cb;
            FUNNEL31(plus0, ca);  FUNNEL31(minus0, na);
            FUNNEL31(plus1, cb);  FUNNEL31(minus1, nb);
        }
    } else {
        // RARE: window contains an exact-zero L1 activation -> exact ternary.
#pragma unroll
        for (int i = 0; i < 2; ++i) {
            uint32_t P[5], M[5];
            {
                uint32_t p16[9], m16[9];
#pragma unroll
                for (int k = 0; k < 9; ++k) {
                    uint32_t a = A[k / 3][i + (k % 3)];
                    uint32_t z = a >> 16;
                    p16[k] = (~(a | z)) & 0xFFFFu;
                    m16[k] = (a & ~z) & 0xFFFFu;
                }
                P[0] = p16[0] | (p16[1] << 16); M[0] = m16[0] | (m16[1] << 16);
                P[1] = p16[2] | (p16[3] << 16); M[1] = m16[2] | (m16[3] << 16);
                P[2] = p16[4] | (p16[5] << 16); M[2] = m16[4] | (m16[5] << 16);
                P[3] = p16[6] | (p16[7] << 16); M[3] = m16[6] | (m16[7] << 16);
                P[4] = p16[8];                  M[4] = m16[8];
            }
            int sp = 0, sm = 0;
#pragma unroll
            for (int g = 0; g < 5; ++g) {
                sp += __builtin_popcount(P[g]);
                sm += __builtin_popcount(M[g]);
            }
            uint32_t pl = 0, mi = 0;
#pragma unroll
            for (int o = 0; o < 23; ++o) {
                int ap = 0, am = 0;
#pragma unroll
                for (int g = 0; g < 5; ++g) {
                    uint32_t Wn = wq[o * 8 + g];
                    ap += __builtin_popcount(P[g] & Wn);
                    am += __builtin_popcount(M[g] & Wn);
                }
                int s = sp - sm + 2 * (am - ap);
                pl |= (uint32_t)(s > 0) << o;
                mi |= (uint32_t)(s < 0) << o;
            }
            if (i == 0) { plus0 = pl; minus0 = mi; }
            else        { plus1 = pl; minus1 = mi; }
        }
    }
    size_t idx = (size_t)b * H2 * STRIDE + (size_t)h * STRIDE + w0;
    *(uint2*)(p2 + idx) = make_uint2(plus0, plus1);
    *(uint2*)(m2 + idx) = make_uint2(minus0, minus1);
}

// 4 px/thread ternary conv -> f32; asm bcnt chains.
__global__ __launch_bounds__(256) void k_conv3(const uint32_t* __restrict__ p2,
                                               const uint32_t* __restrict__ m2,
                                               const uint32_t* __restrict__ pw3,
                                               float* __restrict__ out) {
    int gx = blockIdx.x * 64 + threadIdx.x;   // 0..127
    int h = blockIdx.y * 4 + threadIdx.y;     // 0..507
    int b = blockIdx.z;
    int w0 = gx * 4;
    if (w0 >= H2 || h >= H3) return;
    const uint32_t* pb = p2 + (size_t)b * H2 * STRIDE;
    const uint32_t* mb = m2 + (size_t)b * H2 * STRIDE;
    uint32_t pp[3][6], mm[3][6];
#pragma unroll
    for (int r = 0; r < 3; ++r) {
        const uint32_t* rp = pb + (size_t)(h + r) * STRIDE + w0;
        uint4 q = *(const uint4*)rp;
        uint2 q2 = *(const uint2*)(rp + 4);
        pp[r][0] = q.x; pp[r][1] = q.y; pp[r][2] = q.z; pp[r][3] = q.w;
        pp[r][4] = q2.x; pp[r][5] = q2.y;
        const uint32_t* rm = mb + (size_t)(h + r) * STRIDE + w0;
        uint4 u = *(const uint4*)rm;
        uint2 u2 = *(const uint2*)(rm + 4);
        mm[r][0] = u.x; mm[r][1] = u.y; mm[r][2] = u.z; mm[r][3] = u.w;
        mm[r][4] = u2.x; mm[r][5] = u2.y;
    }
    float val[2][4];
#pragma unroll
    for (int i = 0; i < 4; ++i) {
        int Ps = 0, Ms = 0;
#pragma unroll
        for (int r = 0; r < 3; ++r)
#pragma unroll
            for (int j = 0; j < 3; ++j) {
                BCNT_ACC(Ps, pp[r][i + j]);
                BCNT_ACC(Ms, mm[r][i + j]);
            }
#pragma unroll
        for (int o = 0; o < 2; ++o) {
            int Ap = 0, Am = 0;
#pragma unroll
            for (int r = 0; r < 3; ++r)
#pragma unroll
                for (int j = 0; j < 3; ++j) {
                    uint32_t wm = pw3[o * 9 + r * 3 + j];   // uniform -> SGPR
                    uint32_t ta = pp[r][i + j] & wm;
                    uint32_t tb = mm[r][i + j] & wm;
                    BCNT_ACC(Ap, ta);
                    BCNT_ACC(Am, tb);
                }
            int s = 2 * (Ap - Am) - Ps + Ms;
            val[o][i] = (s > 0) ? 1.f : ((s < 0) ? -1.f : 0.f);
        }
    }
#pragma unroll
    for (int o = 0; o < 2; ++o) {
        float* op = out + (size_t)b * (2 * H3 * H3) + (size_t)o * (H3 * H3) + (size_t)h * H3 + w0;
        *(float2*)op = make_float2(val[o][0], val[o][1]);
        if (w0 + 3 < H3)
            *(float2*)(op + 2) = make_float2(val[o][2], val[o][3]);
    }
}

extern "C" void kernel_launch(void* const* d_in, const int* in_sizes, int n_in,
                              void* d_out, int out_size, void* d_ws, size_t ws_size,
                              hipStream_t stream) {
    const float* inputs = (const float*)d_in[0];
    const float* w1 = (const float*)d_in[1];
    const float* w2 = (const float*)d_in[2];
    const float* w3 = (const float*)d_in[3];
    float* out = (float*)d_out;
    char* ws = (char*)d_ws;

    float* lw = (float*)(ws + 0);             // 448 f32 (reordered sign(w1))
    uint32_t* pw2 = (uint32_t*)(ws + 2048);   // 184 u32 (neg masks, stride 8/o)
    uint32_t* pw3 = (uint32_t*)(ws + 4096);   // 18 u32
    uint32_t* t1 = (uint32_t*)(ws + 8192);    // 32*510*512 u32 (L1: n | z<<16)
    size_t off_p2 = 8192 + (size_t)32 * H1 * STRIDE * 4;
    uint32_t* p2 = (uint32_t*)(ws + off_p2);  // 32*508*512 u32
    size_t off_m2 = off_p2 + (size_t)32 * H2 * STRIDE * 4;
    uint32_t* m2 = (uint32_t*)(ws + off_m2);
    size_t need = off_m2 + (size_t)32 * H2 * STRIDE * 4;
    if (ws_size < need) return;

    hipLaunchKernelGGL(k_prep, dim3(1), dim3(256), 0, stream, w1, w2, w3, lw, pw2, pw3);
    hipLaunchKernelGGL(k_conv1, dim3(2, 64, 32), dim3(64, 4), 0, stream, inputs, lw, t1);
    hipLaunchKernelGGL(k_conv2, dim3(4, 127, 32), dim3(64, 4), 0, stream, t1, pw2, p2, m2);
    hipLaunchKernelGGL(k_conv3, dim3(2, 127, 32), dim3(64, 4), 0, stream, p2, m2, pw3, out);
}

// Round 12
// 197.775 us; speedup vs baseline: 1.3486x; 1.0511x over previous
//
#include <hip/hip_runtime.h>
#include <stdint.h>

// Binarized 3-layer CNN — bit-exact vs float32 reference (verified r3-r11).
// L1: f32 conv, strict sequential (kh,kw,c) per-pixel order, 8 px/thread,
//     weights double-buffered in SGPRs (s_load prefetch one o ahead).
// L2: XOR+popcount vs NEGATIVE masks, 1 px/thread, weights via uniform
//     s_load (stride-5 compact table) in 3 sched_barrier-fenced chunks.
// L3: masked-popcount ternary conv, 4 px/thread (r8-verified).

#define H1 510
#define H2 508
#define H3 506
#define STRIDE 512

#define BCNT_ACC(acc, x) \
    asm("v_bcnt_u32_b32 %0, %1, %0" : "+v"(acc) : "v"(x))
#define FUNNEL31(word, val) \
    asm("v_alignbit_b32 %0, %0, %1, 31" : "+v"(word) : "v"(val))

__global__ __launch_bounds__(256) void k_prep(const float* __restrict__ w1,
                                              const float* __restrict__ w2,
                                              const float* __restrict__ w3,
                                              float* __restrict__ lw,
                                              uint32_t* __restrict__ pw2c,
                                              uint32_t* __restrict__ pw3) {
    int t = threadIdx.x;
    // sign(w1), order t=(r*3+j)*3+c (c fastest), padded to 28/o
    for (int i = t; i < 448; i += 256) {
        int o = i / 28, k = i % 28;
        float v = 0.f;
        if (k < 27) {
            int c = k % 3, j = (k / 3) % 3, r = k / 9;
            float wv = w1[o * 27 + c * 9 + r * 3 + j];
            v = (wv > 0.f) ? 1.f : ((wv < 0.f) ? -1.f : 0.f);
        }
        lw[i] = v;
    }
    // w2 [23][16][3][3] -> pw2c[o*5+g]: NEGATIVE-mask 16-bit channel words,
    // 2 taps/word (k0 lo16, k1 hi16); g==4 hi16 = 0. Compact stride 5.
    for (int i = t; i < 115; i += 256) {
        int o = i / 5, g = i % 5;
        int k0 = 2 * g, k1 = 2 * g + 1;
        uint32_t word = 0;
        for (int c = 0; c < 16; ++c) {
            if (!(w2[o * 144 + c * 9 + k0] > 0.f)) word |= 1u << c;
            if (k1 < 9 && !(w2[o * 144 + c * 9 + k1] > 0.f)) word |= 1u << (16 + c);
        }
        pw2c[i] = word;
    }
    // w3 [2][23][3][3] -> per (o, tap k): POSITIVE 23-bit channel mask
    for (int i = t; i < 18; i += 256) {
        int o = i / 9, k = i % 9;
        uint32_t m = 0;
        for (int c = 0; c < 23; ++c)
            if (w3[o * 207 + c * 9 + k] > 0.f) m |= 1u << c;
        pw3[i] = m;
    }
}

// 8 px/thread (4 wide x 2 tall); strict per-pixel (kh,kw,c) f32 order.
// Weight block for o-1 prefetched via s_load while o's FMAs run.
__global__ __launch_bounds__(256) void k_conv1(const float* __restrict__ in,
                                               const float* __restrict__ lw_g,
                                               uint32_t* __restrict__ t1) {
    int gx = blockIdx.x * 64 + threadIdx.x;   // 0..127
    int hy = blockIdx.y * 4 + threadIdx.y;    // 0..255
    int b = blockIdx.z;
    int w0 = gx * 4;                          // 0..508
    int h0 = hy * 2;                          // 0..510
    if (h0 >= H1) return;
    const float* base = in + (size_t)b * 3 * 512 * 512;
    float x[3][4][6];
    bool tail = (w0 + 4 >= 512);
#pragma unroll
    for (int c = 0; c < 3; ++c)
#pragma unroll
        for (int r = 0; r < 4; ++r) {
            const float* rp = base + c * 262144 + (size_t)(h0 + r) * 512 + w0;
            float4 v4 = *(const float4*)rp;
            x[c][r][0] = v4.x; x[c][r][1] = v4.y; x[c][r][2] = v4.z; x[c][r][3] = v4.w;
            if (!tail) {
                float2 v2 = *(const float2*)(rp + 4);
                x[c][r][4] = v2.x; x[c][r][5] = v2.y;
            } else {
                x[c][r][4] = 0.f; x[c][r][5] = 0.f;   // feeds only px >= H1 (unread)
            }
        }
    uint32_t rn[8] = {0, 0, 0, 0, 0, 0, 0, 0};   // sign-bit planes
    uint32_t rz[8] = {0, 0, 0, 0, 0, 0, 0, 0};   // NONZERO-bit planes
    float wc[28];
    {
        const float* wp = lw_g + 15 * 28;
#pragma unroll
        for (int k = 0; k < 28; ++k) wc[k] = wp[k];   // uniform -> s_load
    }
#pragma unroll 1
    for (int o = 15; o >= 0; --o) {              // o order irrelevant to rounding
        // Prefetch next o's weights (uniform s_load) before the FMA body.
        float wn[28];
        {
            int on = (o > 0) ? (o - 1) : 0;
            const float* wp = lw_g + on * 28;
#pragma unroll
            for (int k = 0; k < 28; ++k) wn[k] = wp[k];
        }
        float s[8];
#pragma unroll
        for (int p = 0; p < 8; ++p) s[p] = 0.f;
#pragma unroll
        for (int t = 0; t < 27; ++t) {           // ascending t = (r*3+j)*3+c
            float wv = wc[t];
            int c = t % 3, j = (t / 3) % 3, r = t / 9;
#pragma unroll
            for (int pr = 0; pr < 2; ++pr)
#pragma unroll
                for (int pc = 0; pc < 4; ++pc)
                    s[pr * 4 + pc] = fmaf(x[c][pr + r][pc + j], wv, s[pr * 4 + pc]);
        }
#pragma unroll
        for (int p = 0; p < 8; ++p) {
            uint32_t u = __float_as_uint(s[p]);
            rn[p] = (rn[p] << 1) | (u >> 31);
            uint32_t nz = u | (0u - u);          // sign set iff u != 0
            rz[p] = (rz[p] << 1) | (nz >> 31);
        }
#pragma unroll
        for (int k = 0; k < 28; ++k) wc[k] = wn[k];  // s_mov swap
    }
    uint32_t* dst = t1 + (size_t)b * H1 * STRIDE;
#pragma unroll
    for (int pr = 0; pr < 2; ++pr) {
        uint32_t w4[4];
#pragma unroll
        for (int pc = 0; pc < 4; ++pc)
            w4[pc] = rn[pr * 4 + pc] | (~rz[pr * 4 + pc] << 16);  // n lo16 | z hi16
        *(uint4*)(dst + (size_t)(h0 + pr) * STRIDE + w0) =
            make_uint4(w4[0], w4[1], w4[2], w4[3]);
    }
}

// 1 px/thread; weights via uniform s_load (SGPRs), chunked to bound pressure.
__global__ __launch_bounds__(256) void k_conv2(const uint32_t* __restrict__ t1,
                                               const uint32_t* __restrict__ wc5,
                                               uint32_t* __restrict__ p2,
                                               uint32_t* __restrict__ m2) {
    int w = blockIdx.x * 64 + threadIdx.x;
    int h = blockIdx.y * 4 + threadIdx.y;
    int b = blockIdx.z;
    if (w >= H2 || h >= H2) return;
    const uint32_t* base = t1 + (size_t)b * H1 * STRIDE;
    uint32_t A[9];
#pragma unroll
    for (int r = 0; r < 3; ++r)
#pragma unroll
        for (int j = 0; j < 3; ++j)
            A[r * 3 + j] = base[(size_t)(h + r) * STRIDE + (w + j)];
    uint32_t orall = A[0] | A[1] | A[2] | A[3] | A[4] | A[5] | A[6] | A[7] | A[8];
    // n-plane packed 2 taps/word via byte-perm
    uint32_t N0 = __builtin_amdgcn_perm(A[1], A[0], 0x05040100u);
    uint32_t N1 = __builtin_amdgcn_perm(A[3], A[2], 0x05040100u);
    uint32_t N2 = __builtin_amdgcn_perm(A[5], A[4], 0x05040100u);
    uint32_t N3 = __builtin_amdgcn_perm(A[7], A[6], 0x05040100u);
    uint32_t N4 = A[8] & 0xFFFFu;
    uint32_t plus = 0, minus = 0;
    if ((orall >> 16) == 0) {
        // FAST: all 144 activations +-1. d = popc_mismatch - 72; o descending.
#define C2O(o) do { \
        uint32_t q0 = wc5[(o) * 5 + 0], q1 = wc5[(o) * 5 + 1], \
                 q2 = wc5[(o) * 5 + 2], q3 = wc5[(o) * 5 + 3], \
                 q4 = wc5[(o) * 5 + 4]; \
        uint32_t t0 = N0 ^ q0, t1v = N1 ^ q1, t2v = N2 ^ q2, \
                 t3v = N3 ^ q3, t4v = N4 ^ q4; \
        int cnt = -72; \
        BCNT_ACC(cnt, t0); BCNT_ACC(cnt, t1v); BCNT_ACC(cnt, t2v); \
        BCNT_ACC(cnt, t3v); BCNT_ACC(cnt, t4v); \
        int nd = -cnt; \
        FUNNEL31(plus, cnt); \
        FUNNEL31(minus, nd); \
    } while (0)
        C2O(22); C2O(21); C2O(20); C2O(19); C2O(18); C2O(17); C2O(16); C2O(15);
        __builtin_amdgcn_sched_barrier(0);
        C2O(14); C2O(13); C2O(12); C2O(11); C2O(10); C2O(9); C2O(8); C2O(7);
        __builtin_amdgcn_sched_barrier(0);
        C2O(6); C2O(5); C2O(4); C2O(3); C2O(2); C2O(1); C2O(0);
#undef C2O
    } else {
        // RARE: window contains an exact-zero L1 activation -> exact ternary.
        uint32_t P[5], M[5];
        {
            uint32_t p16[9], m16[9];
#pragma unroll
            for (int k = 0; k < 9; ++k) {
                uint32_t z = A[k] >> 16;
                p16[k] = (~(A[k] | z)) & 0xFFFFu;
                m16[k] = (A[k] & ~z) & 0xFFFFu;
            }
            P[0] = p16[0] | (p16[1] << 16); M[0] = m16[0] | (m16[1] << 16);
            P[1] = p16[2] | (p16[3] << 16); M[1] = m16[2] | (m16[3] << 16);
            P[2] = p16[4] | (p16[5] << 16); M[2] = m16[4] | (m16[5] << 16);
            P[3] = p16[6] | (p16[7] << 16); M[3] = m16[6] | (m16[7] << 16);
            P[4] = p16[8];                  M[4] = m16[8];
        }
        int sp = 0, sm = 0;
#pragma unroll
        for (int g = 0; g < 5; ++g) {
            sp += __builtin_popcount(P[g]);
            sm += __builtin_popcount(M[g]);
        }
#pragma unroll
        for (int o = 0; o < 23; ++o) {
            int ap = 0, am = 0;
#pragma unroll
            for (int g = 0; g < 5; ++g) {
                uint32_t Wn = wc5[o * 5 + g];   // uniform s_load
                ap += __builtin_popcount(P[g] & Wn);
                am += __builtin_popcount(M[g] & Wn);
            }
            int s = sp - sm + 2 * (am - ap);
            plus  |= (uint32_t)(s > 0) << o;
            minus |= (uint32_t)(s < 0) << o;
        }
    }
    size_t idx = (size_t)b * H2 * STRIDE + (size_t)h * STRIDE + w;
    p2[idx] = plus;
    m2[idx] = minus;
}

// 4 px/thread ternary conv -> f32; asm bcnt chains.
__global__ __launch_bounds__(256) void k_conv3(const uint32_t* __restrict__ p2,
                                               const uint32_t* __restrict__ m2,
                                               const uint32_t* __restrict__ pw3,
                                               float* __restrict__ out) {
    int gx = blockIdx.x * 64 + threadIdx.x;   // 0..127
    int h = blockIdx.y * 4 + threadIdx.y;     // 0..507
    int b = blockIdx.z;
    int w0 = gx * 4;
    if (w0 >= H2 || h >= H3) return;
    const uint32_t* pb = p2 + (size_t)b * H2 * STRIDE;
    const uint32_t* mb = m2 + (size_t)b * H2 * STRIDE;
    uint32_t pp[3][6], mm[3][6];
#pragma unroll
    for (int r = 0; r < 3; ++r) {
        const uint32_t* rp = pb + (size_t)(h + r) * STRIDE + w0;
        uint4 q = *(const uint4*)rp;
        uint2 q2 = *(const uint2*)(rp + 4);
        pp[r][0] = q.x; pp[r][1] = q.y; pp[r][2] = q.z; pp[r][3] = q.w;
        pp[r][4] = q2.x; pp[r][5] = q2.y;
        const uint32_t* rm = mb + (size_t)(h + r) * STRIDE + w0;
        uint4 u = *(const uint4*)rm;
        uint2 u2 = *(const uint2*)(rm + 4);
        mm[r][0] = u.x; mm[r][1] = u.y; mm[r][2] = u.z; mm[r][3] = u.w;
        mm[r][4] = u2.x; mm[r][5] = u2.y;
    }
    float val[2][4];
#pragma unroll
    for (int i = 0; i < 4; ++i) {
        int Ps = 0, Ms = 0;
#pragma unroll
        for (int r = 0; r < 3; ++r)
#pragma unroll
            for (int j = 0; j < 3; ++j) {
                BCNT_ACC(Ps, pp[r][i + j]);
                BCNT_ACC(Ms, mm[r][i + j]);
            }
#pragma unroll
        for (int o = 0; o < 2; ++o) {
            int Ap = 0, Am = 0;
#pragma unroll
            for (int r = 0; r < 3; ++r)
#pragma unroll
                for (int j = 0; j < 3; ++j) {
                    uint32_t wm = pw3[o * 9 + r * 3 + j];   // uniform -> SGPR
                    uint32_t ta = pp[r][i + j] & wm;
                    uint32_t tb = mm[r][i + j] & wm;
                    BCNT_ACC(Ap, ta);
                    BCNT_ACC(Am, tb);
                }
            int s = 2 * (Ap - Am) - Ps + Ms;
            val[o][i] = (s > 0) ? 1.f : ((s < 0) ? -1.f : 0.f);
        }
    }
#pragma unroll
    for (int o = 0; o < 2; ++o) {
        float* op = out + (size_t)b * (2 * H3 * H3) + (size_t)o * (H3 * H3) + (size_t)h * H3 + w0;
        *(float2*)op = make_float2(val[o][0], val[o][1]);
        if (w0 + 3 < H3)
            *(float2*)(op + 2) = make_float2(val[o][2], val[o][3]);
    }
}

extern "C" void kernel_launch(void* const* d_in, const int* in_sizes, int n_in,
                              void* d_out, int out_size, void* d_ws, size_t ws_size,
                              hipStream_t stream) {
    const float* inputs = (const float*)d_in[0];
    const float* w1 = (const float*)d_in[1];
    const float* w2 = (const float*)d_in[2];
    const float* w3 = (const float*)d_in[3];
    float* out = (float*)d_out;
    char* ws = (char*)d_ws;

    float* lw = (float*)(ws + 0);             // 448 f32 (reordered sign(w1))
    uint32_t* pw2c = (uint32_t*)(ws + 2048);  // 115 u32 (neg masks, stride 5)
    uint32_t* pw3 = (uint32_t*)(ws + 4096);   // 18 u32
    uint32_t* t1 = (uint32_t*)(ws + 8192);    // 32*510*512 u32 (L1: n | z<<16)
    size_t off_p2 = 8192 + (size_t)32 * H1 * STRIDE * 4;
    uint32_t* p2 = (uint32_t*)(ws + off_p2);  // 32*508*512 u32
    size_t off_m2 = off_p2 + (size_t)32 * H2 * STRIDE * 4;
    uint32_t* m2 = (uint32_t*)(ws + off_m2);
    size_t need = off_m2 + (size_t)32 * H2 * STRIDE * 4;
    if (ws_size < need) return;

    hipLaunchKernelGGL(k_prep, dim3(1), dim3(256), 0, stream, w1, w2, w3, lw, pw2c, pw3);
    hipLaunchKernelGGL(k_conv1, dim3(2, 64, 32), dim3(64, 4), 0, stream, inputs, lw, t1);
    hipLaunchKernelGGL(k_conv2, dim3(8, 127, 32), dim3(64, 4), 0, stream, t1, pw2c, p2, m2);
    hipLaunchKernelGGL(k_conv3, dim3(2, 127, 32), dim3(64, 4), 0, stream, p2, m2, pw3, out);
}